// Round 14
// baseline (876.415 us; speedup 1.0000x reference)
//
#include <hip/hip_runtime.h>

// out[B=1024, O=8192] = x[B, I=16384] @ (W*mask)[O, I]^T + bias[O]
// Phase 1: W*mask -> bf16 (ws), x -> bf16 (ws), nontemporal streaming.
// Phase 2: 256x256 bf16 MFMA GEMM, split-K=2, grid 256 (1 block/CU),
//          16 waves (4x4, 64x64/wave). B staged in LDS (XOR-swizzled,
//          0 conflicts); A read DIRECT from global (L1 serves the 4x
//          wc-duplicates; one 128B line per row per tile). One vmcnt(0)
//          (non-stalling) + one barrier per K-tile (r12-verified form).
// Phase 3: reduce partials + bias.

#define IN_DIM 16384
#define OUT_DIM 8192
#define BATCH 1024

#define BM 256
#define BN 256
#define BK 64
#define KSPLIT 2
#define K_HALF (IN_DIM / KSPLIT)  // 8192
#define NT_K (K_HALF / BK)        // 128
#define NT256 (OUT_DIM / BN)      // 32
#define MT256 (BATCH / BM)        // 4

typedef __attribute__((ext_vector_type(8))) short bf16x8;
typedef __attribute__((ext_vector_type(4))) float f32x4;
typedef __attribute__((ext_vector_type(8))) unsigned short u16x8;

__device__ __forceinline__ unsigned short f2bf(float f) {
  unsigned int u = __float_as_uint(f);
  return (unsigned short)((u + 0x7fffu + ((u >> 16) & 1u)) >> 16);
}

#define GL16(g, l)                                                \
  __builtin_amdgcn_global_load_lds(                               \
      (const __attribute__((address_space(1))) void*)(g),         \
      (__attribute__((address_space(3))) void*)(l), 16, 0, 0)

__global__ __launch_bounds__(256) void prep_w_kernel(
    const f32x4* __restrict__ w, const f32x4* __restrict__ m,
    u16x8* __restrict__ out, int n8) {
  int i = blockIdx.x * blockDim.x + threadIdx.x;
  int stride = gridDim.x * blockDim.x;
  for (; i < n8; i += stride) {
    f32x4 w0 = __builtin_nontemporal_load(&w[2 * i]);
    f32x4 w1 = __builtin_nontemporal_load(&w[2 * i + 1]);
    f32x4 m0 = __builtin_nontemporal_load(&m[2 * i]);
    f32x4 m1 = __builtin_nontemporal_load(&m[2 * i + 1]);
    u16x8 o;
    o[0] = f2bf(w0[0] * m0[0]);
    o[1] = f2bf(w0[1] * m0[1]);
    o[2] = f2bf(w0[2] * m0[2]);
    o[3] = f2bf(w0[3] * m0[3]);
    o[4] = f2bf(w1[0] * m1[0]);
    o[5] = f2bf(w1[1] * m1[1]);
    o[6] = f2bf(w1[2] * m1[2]);
    o[7] = f2bf(w1[3] * m1[3]);
    __builtin_nontemporal_store(o, &out[i]);
  }
}

__global__ __launch_bounds__(256) void prep_x_kernel(
    const f32x4* __restrict__ x, u16x8* __restrict__ out, int n8) {
  int i = blockIdx.x * blockDim.x + threadIdx.x;
  int stride = gridDim.x * blockDim.x;
  for (; i < n8; i += stride) {
    f32x4 v0 = __builtin_nontemporal_load(&x[2 * i]);
    f32x4 v1 = __builtin_nontemporal_load(&x[2 * i + 1]);
    u16x8 o;
    o[0] = f2bf(v0[0]);
    o[1] = f2bf(v0[1]);
    o[2] = f2bf(v0[2]);
    o[3] = f2bf(v0[3]);
    o[4] = f2bf(v1[0]);
    o[5] = f2bf(v1[1]);
    o[6] = f2bf(v1[2]);
    o[7] = f2bf(v1[3]);
    __builtin_nontemporal_store(o, &out[i]);
  }
}

__global__ __launch_bounds__(256) void reduce_kernel(
    const f32x4* __restrict__ p0, const f32x4* __restrict__ p1,
    const f32x4* __restrict__ bias4, f32x4* __restrict__ out, int n4) {
  int i = blockIdx.x * blockDim.x + threadIdx.x;
  int stride = gridDim.x * blockDim.x;
  for (; i < n4; i += stride) {
    f32x4 a = p0[i];
    f32x4 b = p1[i];
    f32x4 c = bias4[i & (OUT_DIM / 4 - 1)];
    out[i] = a + b + c;
  }
}

// 256x256 tile, 16 waves (4M x 4N), per-wave 64x64, split-K=2.
// bid = (mt*2+kh)*32 + nt -> all sharers of N-panel nt on one XCD.
// B: LDS [slot][256][64] shorts, 2 slots (64 KiB). A: global-direct.
// Per tile t (slot cur=t&1, o=cur^1):
//   vmcnt(0)  [B(t) staged a full window ago -> retired -> no stall;
//              A-loads of t-1 already consumed by their MFMAs]
//   s_barrier [publishes B(t) resident; licenses overwrite of slot o]
//   STAGE_B(t+1 -> o)  [flies during the whole window-t compute]
//   compute: 8 LDS bF reads + 8 global aF reads + 32 MFMA, compiler-scheduled
__global__ __launch_bounds__(1024, 4) void gemm256(
    const short* __restrict__ Ab, const short* __restrict__ Bb,
    float* __restrict__ out0, float* __restrict__ out1) {
  __shared__ short Bs[2][256 * 64];  // 2 x 32 KB

  const int tid = threadIdx.x;
  const int lane = tid & 63;
  const int wv = tid >> 6;   // 0..15
  const int wr = wv >> 2;    // 0..3
  const int wc = wv & 3;     // 0..3
  const int fr = lane & 15;
  const int fq = lane >> 4;  // 0..3

  const int bid = blockIdx.x;
  const int nt = bid & (NT256 - 1);
  const int rest = bid >> 5;  // mt*2 + kh
  const int mt = rest >> 1;
  const int kh = rest & 1;
  const int row0 = mt * BM;
  const int col0 = nt * BN;
  const int kbase = kh * K_HALF;
  float* __restrict__ dst = kh ? out1 : out0;

  // B staging: per GL16 issue, 1024 threads cover 128 rows x 64 cols (16 KB).
  // thread -> row tid>>3, 16B chunk (tid&7); source chunk XOR-swizzled by
  // row&7 (rule 21: linear LDS dest, swizzled source + swizzled read).
  const int swz8 = ((tid & 7) ^ ((tid >> 3) & 7)) * 8;  // elements
  const short* srcB = Bb + (size_t)(col0 + (tid >> 3)) * IN_DIM + kbase + swz8;
  char* ldsB = (char*)Bs;
  const int stg = wv * 1024;  // wave-uniform slice within a 16 KB issue

#define STAGE_B(KT, SL)                                                    \
  do {                                                                     \
    GL16(srcB + (size_t)(KT)*64, ldsB + (SL)*32768 + stg);                 \
    GL16(srcB + (size_t)128 * IN_DIM + (size_t)(KT)*64,                    \
         ldsB + (SL)*32768 + 16384 + stg);                                 \
  } while (0)

  // B ds_read: frag at tile row R, kchunk cg=ks*4+fq lives at byte
  //   slot*32768 + R*128 + ((cg ^ (R&7))*16);  R&7 == fr&7 for all frags.
  const int swzslot = (fq ^ (fr & 7)) * 16;
  const int Bbase = (wc * 64 + fr) * 128 + swzslot;

  // A global-direct: lane (fr,fq), frag (m,ks) reads 16B at
  //   A[row0 + wr*64 + m*16 + fr][kbase + t*64 + ks*32 + fq*8]
  // For one row: fq x ks spans 128B = one L1 line; wc-duplicates hit L1.
  const short* srcA =
      Ab + (size_t)(row0 + wr * 64 + fr) * IN_DIM + kbase + fq * 8;

  f32x4 acc[4][4];
#pragma unroll
  for (int i = 0; i < 4; ++i)
#pragma unroll
    for (int j = 0; j < 4; ++j) acc[i][j] = (f32x4)0.f;

  // Prologue: B tile 0 -> slot 0.
  STAGE_B(0, 0);

#pragma unroll 1
  for (int t = 0; t < NT_K; ++t) {
    const int cur = t & 1;
    // Non-stalling in steady state: only B(t)'s 2 loads (issued one full
    // window ago) can remain; A-loads of t-1 were consumed by their MFMAs.
    asm volatile("s_waitcnt vmcnt(0)" ::: "memory");
    __builtin_amdgcn_s_barrier();
    if (t + 1 < NT_K) STAGE_B(t + 1, cur ^ 1);

    const char* tB = (const char*)Bs + cur * 32768;
    const short* aRow = srcA + (size_t)t * 64;
#pragma unroll
    for (int ks = 0; ks < 2; ++ks) {
      const int off = ks << 6;
      bf16x8 bF[4];
#pragma unroll
      for (int n = 0; n < 4; ++n)
        bF[n] = *(const bf16x8*)(tB + ((Bbase + n * 2048) ^ off));
#pragma unroll
      for (int m = 0; m < 4; ++m) {
        bf16x8 aF =
            *(const bf16x8*)(aRow + (size_t)(m * 16) * IN_DIM + ks * 32);
#pragma unroll
        for (int n = 0; n < 4; ++n)
          acc[m][n] = __builtin_amdgcn_mfma_f32_16x16x32_bf16(aF, bF[n],
                                                              acc[m][n], 0, 0,
                                                              0);
      }
    }
  }

  // C/D layout: col = lane&15, row = (lane>>4)*4 + reg
#pragma unroll
  for (int m = 0; m < 4; ++m) {
#pragma unroll
    for (int n = 0; n < 4; ++n) {
      const int c = col0 + wc * 64 + n * 16 + fr;
      const int rb = row0 + wr * 64 + m * 16 + fq * 4;
#pragma unroll
      for (int tt = 0; tt < 4; ++tt)
        dst[(size_t)(rb + tt) * OUT_DIM + c] = acc[m][n][tt];
    }
  }
#undef STAGE_B
}

// Fallback (ws too small): fused f32->bf16 128x128 kernel, verified round 1.
__global__ __launch_bounds__(256) void gemm128_fused(
    const float* __restrict__ X, const float* __restrict__ W,
    const float* __restrict__ Msk, const float* __restrict__ bias,
    float* __restrict__ out) {
  __shared__ short As[128 * 64];
  __shared__ short Bs[128 * 64];
  const int tid = threadIdx.x;
  const int lane = tid & 63;
  const int wv4 = tid >> 6;
  const int wm = wv4 >> 1;
  const int wn = wv4 & 1;
  const int fr = lane & 15;
  const int fq = lane >> 4;
  const int bid = blockIdx.x;
  const int nt = bid & 63;
  const int mt = bid >> 6;
  const int row0 = mt * 128;
  const int col0 = nt * 128;
  f32x4 acc[4][4];
#pragma unroll
  for (int i = 0; i < 4; ++i)
#pragma unroll
    for (int j = 0; j < 4; ++j) acc[i][j] = (f32x4)0.f;
  for (int kt = 0; kt < IN_DIM / 64; ++kt) {
    const int k0 = kt * 64;
    __syncthreads();
#pragma unroll
    for (int is = 0; is < 4; ++is) {
      const int e = (is * 256 + tid) * 8;
      const int r = e >> 6;
      const int kk = e & 63;
      {
        const float* src = X + (size_t)(row0 + r) * IN_DIM + k0 + kk;
        f32x4 a0 = *(const f32x4*)src;
        f32x4 a1 = *(const f32x4*)(src + 4);
        bf16x8 v;
        v[0] = (short)f2bf(a0[0]); v[1] = (short)f2bf(a0[1]);
        v[2] = (short)f2bf(a0[2]); v[3] = (short)f2bf(a0[3]);
        v[4] = (short)f2bf(a1[0]); v[5] = (short)f2bf(a1[1]);
        v[6] = (short)f2bf(a1[2]); v[7] = (short)f2bf(a1[3]);
        *(bf16x8*)&As[r * 64 + kk] = v;
      }
      {
        const float* sw = W + (size_t)(col0 + r) * IN_DIM + k0 + kk;
        const float* sm = Msk + (size_t)(col0 + r) * IN_DIM + k0 + kk;
        f32x4 w0 = *(const f32x4*)sw;
        f32x4 w1 = *(const f32x4*)(sw + 4);
        f32x4 m0 = *(const f32x4*)sm;
        f32x4 m1 = *(const f32x4*)(sm + 4);
        bf16x8 v;
        v[0] = (short)f2bf(w0[0] * m0[0]); v[1] = (short)f2bf(w0[1] * m0[1]);
        v[2] = (short)f2bf(w0[2] * m0[2]); v[3] = (short)f2bf(w0[3] * m0[3]);
        v[4] = (short)f2bf(w1[0] * m1[0]); v[5] = (short)f2bf(w1[1] * m1[1]);
        v[6] = (short)f2bf(w1[2] * m1[2]); v[7] = (short)f2bf(w1[3] * m1[3]);
        *(bf16x8*)&Bs[r * 64 + kk] = v;
      }
    }
    __syncthreads();
#pragma unroll
    for (int ks = 0; ks < 2; ++ks) {
      bf16x8 af[4], bf[4];
#pragma unroll
      for (int i = 0; i < 4; ++i)
        af[i] = *(const bf16x8*)&As[(wm * 64 + i * 16 + fr) * 64 + ks * 32 + fq * 8];
#pragma unroll
      for (int j = 0; j < 4; ++j)
        bf[j] = *(const bf16x8*)&Bs[(wn * 64 + j * 16 + fr) * 64 + ks * 32 + fq * 8];
#pragma unroll
      for (int i = 0; i < 4; ++i)
#pragma unroll
        for (int j = 0; j < 4; ++j)
          acc[i][j] = __builtin_amdgcn_mfma_f32_16x16x32_bf16(af[i], bf[j],
                                                              acc[i][j], 0, 0, 0);
    }
  }
#pragma unroll
  for (int j = 0; j < 4; ++j) {
    const int c = col0 + wn * 64 + j * 16 + fr;
    const float bv = bias[c];
#pragma unroll
    for (int i = 0; i < 4; ++i) {
      const int rb = row0 + wm * 64 + i * 16 + fq * 4;
#pragma unroll
      for (int tt = 0; tt < 4; ++tt)
        out[(size_t)(rb + tt) * OUT_DIM + c] = acc[i][j][tt] + bv;
    }
  }
}

extern "C" void kernel_launch(void* const* d_in, const int* in_sizes, int n_in,
                              void* d_out, int out_size, void* d_ws, size_t ws_size,
                              hipStream_t stream) {
  const float* x = (const float*)d_in[0];
  const float* w = (const float*)d_in[1];
  const float* bias = (const float*)d_in[2];
  const float* mask = (const float*)d_in[3];
  float* out = (float*)d_out;

  const size_t wm_elems = (size_t)OUT_DIM * IN_DIM;
  const size_t xb_elems = (size_t)BATCH * IN_DIM;
  const size_t out_elems = (size_t)BATCH * OUT_DIM;
  const size_t need_bf16 = (wm_elems + xb_elems) * sizeof(short);   // 288 MiB
  const size_t need_split = need_bf16 + out_elems * sizeof(float);  // 320 MiB

  if (ws_size >= need_split) {
    short* wmb = (short*)d_ws;
    short* xbb = wmb + wm_elems;
    float* p1 = (float*)((char*)d_ws + need_bf16);
    hipLaunchKernelGGL(prep_w_kernel, dim3(4096), dim3(256), 0, stream,
                       (const f32x4*)w, (const f32x4*)mask, (u16x8*)wmb,
                       (int)(wm_elems / 8));
    hipLaunchKernelGGL(prep_x_kernel, dim3(512), dim3(256), 0, stream,
                       (const f32x4*)x, (u16x8*)xbb, (int)(xb_elems / 8));
    hipLaunchKernelGGL(gemm256, dim3(KSPLIT * MT256 * NT256), dim3(1024), 0,
                       stream, xbb, wmb, out, p1);
    hipLaunchKernelGGL(reduce_kernel, dim3(2048), dim3(256), 0, stream,
                       (const f32x4*)out, (const f32x4*)p1,
                       (const f32x4*)bias, (f32x4*)out, (int)(out_elems / 4));
  } else {
    hipLaunchKernelGGL(gemm128_fused, dim3(512), dim3(256), 0, stream, x, w,
                       mask, bias, out);
  }
}

// Round 15
// 552.195 us; speedup vs baseline: 1.5871x; 1.5871x over previous
//
#include <hip/hip_runtime.h>

// out[B=1024, O=8192] = x[B, I=16384] @ (W*mask)[O, I]^T + bias[O]
// FINAL (r11 configuration — best measured: 551 us total, gemm 320 us):
// Phase 1: W*mask -> bf16 (ws), x -> bf16 (ws), nontemporal streaming
//          (prep_w at the ~208 us HBM floor for 1.31 GB moved).
// Phase 2: 256x256 bf16 MFMA GEMM, split-K=2, grid 256 (1 block/CU),
//          16 waves (4x4 grid, 64x64/wave, acc=64 regs -> 4 waves/SIMD),
//          2-barrier/tile counted-vmcnt(4) single-type ledger,
//          XOR-swizzled LDS (0 bank conflicts, verified r5-r13).
// Phase 3: reduce partials + bias.

#define IN_DIM 16384
#define OUT_DIM 8192
#define BATCH 1024

#define BM 256
#define BN 256
#define BK 64
#define KSPLIT 2
#define K_HALF (IN_DIM / KSPLIT)  // 8192
#define NT_K (K_HALF / BK)        // 128
#define NT256 (OUT_DIM / BN)      // 32
#define MT256 (BATCH / BM)        // 4

typedef __attribute__((ext_vector_type(8))) short bf16x8;
typedef __attribute__((ext_vector_type(4))) float f32x4;
typedef __attribute__((ext_vector_type(8))) unsigned short u16x8;

__device__ __forceinline__ unsigned short f2bf(float f) {
  unsigned int u = __float_as_uint(f);
  return (unsigned short)((u + 0x7fffu + ((u >> 16) & 1u)) >> 16);
}

#define GL16(g, l)                                                \
  __builtin_amdgcn_global_load_lds(                               \
      (const __attribute__((address_space(1))) void*)(g),         \
      (__attribute__((address_space(3))) void*)(l), 16, 0, 0)

__global__ __launch_bounds__(256) void prep_w_kernel(
    const f32x4* __restrict__ w, const f32x4* __restrict__ m,
    u16x8* __restrict__ out, int n8) {
  int i = blockIdx.x * blockDim.x + threadIdx.x;
  int stride = gridDim.x * blockDim.x;
  for (; i < n8; i += stride) {
    f32x4 w0 = __builtin_nontemporal_load(&w[2 * i]);
    f32x4 w1 = __builtin_nontemporal_load(&w[2 * i + 1]);
    f32x4 m0 = __builtin_nontemporal_load(&m[2 * i]);
    f32x4 m1 = __builtin_nontemporal_load(&m[2 * i + 1]);
    u16x8 o;
    o[0] = f2bf(w0[0] * m0[0]);
    o[1] = f2bf(w0[1] * m0[1]);
    o[2] = f2bf(w0[2] * m0[2]);
    o[3] = f2bf(w0[3] * m0[3]);
    o[4] = f2bf(w1[0] * m1[0]);
    o[5] = f2bf(w1[1] * m1[1]);
    o[6] = f2bf(w1[2] * m1[2]);
    o[7] = f2bf(w1[3] * m1[3]);
    __builtin_nontemporal_store(o, &out[i]);
  }
}

__global__ __launch_bounds__(256) void prep_x_kernel(
    const f32x4* __restrict__ x, u16x8* __restrict__ out, int n8) {
  int i = blockIdx.x * blockDim.x + threadIdx.x;
  int stride = gridDim.x * blockDim.x;
  for (; i < n8; i += stride) {
    f32x4 v0 = __builtin_nontemporal_load(&x[2 * i]);
    f32x4 v1 = __builtin_nontemporal_load(&x[2 * i + 1]);
    u16x8 o;
    o[0] = f2bf(v0[0]);
    o[1] = f2bf(v0[1]);
    o[2] = f2bf(v0[2]);
    o[3] = f2bf(v0[3]);
    o[4] = f2bf(v1[0]);
    o[5] = f2bf(v1[1]);
    o[6] = f2bf(v1[2]);
    o[7] = f2bf(v1[3]);
    __builtin_nontemporal_store(o, &out[i]);
  }
}

__global__ __launch_bounds__(256) void reduce_kernel(
    const f32x4* __restrict__ p0, const f32x4* __restrict__ p1,
    const f32x4* __restrict__ bias4, f32x4* __restrict__ out, int n4) {
  int i = blockIdx.x * blockDim.x + threadIdx.x;
  int stride = gridDim.x * blockDim.x;
  for (; i < n4; i += stride) {
    f32x4 a = p0[i];
    f32x4 b = p1[i];
    f32x4 c = bias4[i & (OUT_DIM / 4 - 1)];
    out[i] = a + b + c;
  }
}

// 256x256 tile, 16 waves (4M x 4N), per-wave 64x64, split-K=2.
// bid = (mt*2+kh)*32 + nt -> all sharers of N-panel nt on one XCD.
// LDS [slot][256][64] shorts per matrix (2 slots, 128 KiB total).
// Per tile t (slot cur=t&1, o=cur^1):
//   STAGE A,B(t+1)->o (4 GL16/thread); vmcnt(4) [single-type FIFO: retires
//   tile t's 4, leaves t+1's 4 in flight]; barrier; compute slot cur
//   (compiler-scheduled ds_read/MFMA interleave, no pinning); barrier.
__global__ __launch_bounds__(1024, 4) void gemm256(
    const short* __restrict__ Ab, const short* __restrict__ Bb,
    float* __restrict__ out0, float* __restrict__ out1) {
  __shared__ short As[2][256 * 64];  // 2 x 32 KB
  __shared__ short Bs[2][256 * 64];  // 2 x 32 KB

  const int tid = threadIdx.x;
  const int lane = tid & 63;
  const int wv = tid >> 6;   // 0..15
  const int wr = wv >> 2;    // 0..3
  const int wc = wv & 3;     // 0..3
  const int fr = lane & 15;
  const int fq = lane >> 4;  // 0..3

  const int bid = blockIdx.x;
  const int nt = bid & (NT256 - 1);
  const int rest = bid >> 5;  // mt*2 + kh
  const int mt = rest >> 1;
  const int kh = rest & 1;
  const int row0 = mt * BM;
  const int col0 = nt * BN;
  const int kbase = kh * K_HALF;
  float* __restrict__ dst = kh ? out1 : out0;

  // Staging: per GL16 issue, 1024 threads cover 128 rows x 64 cols (16 KB).
  // thread -> row tid>>3, 16B chunk (tid&7); source chunk XOR-swizzled by
  // row&7 (rule 21: linear LDS dest, swizzled source + swizzled read).
  const int swz8 = ((tid & 7) ^ ((tid >> 3) & 7)) * 8;  // elements
  const short* srcA = Ab + (size_t)(row0 + (tid >> 3)) * IN_DIM + kbase + swz8;
  const short* srcB = Bb + (size_t)(col0 + (tid >> 3)) * IN_DIM + kbase + swz8;
  char* ldsA = (char*)As;
  char* ldsB = (char*)Bs;
  const int stg = wv * 1024;  // wave-uniform slice within a 16 KB issue

#define STAGE_A(KT, SL)                                                    \
  do {                                                                     \
    GL16(srcA + (size_t)(KT)*64, ldsA + (SL)*32768 + stg);                 \
    GL16(srcA + (size_t)128 * IN_DIM + (size_t)(KT)*64,                    \
         ldsA + (SL)*32768 + 16384 + stg);                                 \
  } while (0)
#define STAGE_B(KT, SL)                                                    \
  do {                                                                     \
    GL16(srcB + (size_t)(KT)*64, ldsB + (SL)*32768 + stg);                 \
    GL16(srcB + (size_t)128 * IN_DIM + (size_t)(KT)*64,                    \
         ldsB + (SL)*32768 + 16384 + stg);                                 \
  } while (0)

  // ds_read: frag at tile row R, kchunk cg=ks*4+fq lives at byte
  //   slot*32768 + R*128 + ((cg ^ (R&7))*16);  R&7 == fr&7 for all frags.
  const int swzslot = (fq ^ (fr & 7)) * 16;
  const int Abase = (wr * 64 + fr) * 128 + swzslot;
  const int Bbase = (wc * 64 + fr) * 128 + swzslot;

  f32x4 acc[4][4];
#pragma unroll
  for (int i = 0; i < 4; ++i)
#pragma unroll
    for (int j = 0; j < 4; ++j) acc[i][j] = (f32x4)0.f;

  // Prologue: tile 0 -> slot 0.
  STAGE_A(0, 0);
  STAGE_B(0, 0);

#pragma unroll 1
  for (int t = 0; t < NT_K; ++t) {
    const int cur = t & 1;
    if (t + 1 < NT_K) {
      STAGE_A(t + 1, cur ^ 1);
      STAGE_B(t + 1, cur ^ 1);
      // Single-type FIFO: 8 outstanding (4 of tile t + 4 of t+1);
      // vmcnt(4) certifies all of tile t, leaves t+1 in flight.
      asm volatile("s_waitcnt vmcnt(4)" ::: "memory");
    } else {
      asm volatile("s_waitcnt vmcnt(0)" ::: "memory");
    }
    __builtin_amdgcn_s_barrier();  // tile t resident for all waves

    const char* tA = (const char*)As + cur * 32768;
    const char* tB = (const char*)Bs + cur * 32768;
#pragma unroll
    for (int ks = 0; ks < 2; ++ks) {
      const int off = ks << 6;
      bf16x8 bF[4];
#pragma unroll
      for (int n = 0; n < 4; ++n)
        bF[n] = *(const bf16x8*)(tB + ((Bbase + n * 2048) ^ off));
#pragma unroll
      for (int m = 0; m < 4; ++m) {
        bf16x8 aF = *(const bf16x8*)(tA + ((Abase + m * 2048) ^ off));
#pragma unroll
        for (int n = 0; n < 4; ++n)
          acc[m][n] = __builtin_amdgcn_mfma_f32_16x16x32_bf16(aF, bF[n],
                                                              acc[m][n], 0, 0,
                                                              0);
      }
    }
    __builtin_amdgcn_s_barrier();  // all reads of slot cur done -> next
                                   // iteration may overwrite it
  }

  // C/D layout: col = lane&15, row = (lane>>4)*4 + reg
#pragma unroll
  for (int m = 0; m < 4; ++m) {
#pragma unroll
    for (int n = 0; n < 4; ++n) {
      const int c = col0 + wc * 64 + n * 16 + fr;
      const int rb = row0 + wr * 64 + m * 16 + fq * 4;
#pragma unroll
      for (int tt = 0; tt < 4; ++tt)
        dst[(size_t)(rb + tt) * OUT_DIM + c] = acc[m][n][tt];
    }
  }
#undef STAGE_A
#undef STAGE_B
}

// Fallback (ws too small): fused f32->bf16 128x128 kernel, verified round 1.
__global__ __launch_bounds__(256) void gemm128_fused(
    const float* __restrict__ X, const float* __restrict__ W,
    const float* __restrict__ Msk, const float* __restrict__ bias,
    float* __restrict__ out) {
  __shared__ short As[128 * 64];
  __shared__ short Bs[128 * 64];
  const int tid = threadIdx.x;
  const int lane = tid & 63;
  const int wv4 = tid >> 6;
  const int wm = wv4 >> 1;
  const int wn = wv4 & 1;
  const int fr = lane & 15;
  const int fq = lane >> 4;
  const int bid = blockIdx.x;
  const int nt = bid & 63;
  const int mt = bid >> 6;
  const int row0 = mt * 128;
  const int col0 = nt * 128;
  f32x4 acc[4][4];
#pragma unroll
  for (int i = 0; i < 4; ++i)
#pragma unroll
    for (int j = 0; j < 4; ++j) acc[i][j] = (f32x4)0.f;
  for (int kt = 0; kt < IN_DIM / 64; ++kt) {
    const int k0 = kt * 64;
    __syncthreads();
#pragma unroll
    for (int is = 0; is < 4; ++is) {
      const int e = (is * 256 + tid) * 8;
      const int r = e >> 6;
      const int kk = e & 63;
      {
        const float* src = X + (size_t)(row0 + r) * IN_DIM + k0 + kk;
        f32x4 a0 = *(const f32x4*)src;
        f32x4 a1 = *(const f32x4*)(src + 4);
        bf16x8 v;
        v[0] = (short)f2bf(a0[0]); v[1] = (short)f2bf(a0[1]);
        v[2] = (short)f2bf(a0[2]); v[3] = (short)f2bf(a0[3]);
        v[4] = (short)f2bf(a1[0]); v[5] = (short)f2bf(a1[1]);
        v[6] = (short)f2bf(a1[2]); v[7] = (short)f2bf(a1[3]);
        *(bf16x8*)&As[r * 64 + kk] = v;
      }
      {
        const float* sw = W + (size_t)(col0 + r) * IN_DIM + k0 + kk;
        const float* sm = Msk + (size_t)(col0 + r) * IN_DIM + k0 + kk;
        f32x4 w0 = *(const f32x4*)sw;
        f32x4 w1 = *(const f32x4*)(sw + 4);
        f32x4 m0 = *(const f32x4*)sm;
        f32x4 m1 = *(const f32x4*)(sm + 4);
        bf16x8 v;
        v[0] = (short)f2bf(w0[0] * m0[0]); v[1] = (short)f2bf(w0[1] * m0[1]);
        v[2] = (short)f2bf(w0[2] * m0[2]); v[3] = (short)f2bf(w0[3] * m0[3]);
        v[4] = (short)f2bf(w1[0] * m1[0]); v[5] = (short)f2bf(w1[1] * m1[1]);
        v[6] = (short)f2bf(w1[2] * m1[2]); v[7] = (short)f2bf(w1[3] * m1[3]);
        *(bf16x8*)&Bs[r * 64 + kk] = v;
      }
    }
    __syncthreads();
#pragma unroll
    for (int ks = 0; ks < 2; ++ks) {
      bf16x8 af[4], bf[4];
#pragma unroll
      for (int i = 0; i < 4; ++i)
        af[i] = *(const bf16x8*)&As[(wm * 64 + i * 16 + fr) * 64 + ks * 32 + fq * 8];
#pragma unroll
      for (int j = 0; j < 4; ++j)
        bf[j] = *(const bf16x8*)&Bs[(wn * 64 + j * 16 + fr) * 64 + ks * 32 + fq * 8];
#pragma unroll
      for (int i = 0; i < 4; ++i)
#pragma unroll
        for (int j = 0; j < 4; ++j)
          acc[i][j] = __builtin_amdgcn_mfma_f32_16x16x32_bf16(af[i], bf[j],
                                                              acc[i][j], 0, 0, 0);
    }
  }
#pragma unroll
  for (int j = 0; j < 4; ++j) {
    const int c = col0 + wn * 64 + j * 16 + fr;
    const float bv = bias[c];
#pragma unroll
    for (int i = 0; i < 4; ++i) {
      const int rb = row0 + wm * 64 + i * 16 + fq * 4;
#pragma unroll
      for (int tt = 0; tt < 4; ++tt)
        out[(size_t)(rb + tt) * OUT_DIM + c] = acc[i][j][tt] + bv;
    }
  }
}

extern "C" void kernel_launch(void* const* d_in, const int* in_sizes, int n_in,
                              void* d_out, int out_size, void* d_ws, size_t ws_size,
                              hipStream_t stream) {
  const float* x = (const float*)d_in[0];
  const float* w = (const float*)d_in[1];
  const float* bias = (const float*)d_in[2];
  const float* mask = (const float*)d_in[3];
  float* out = (float*)d_out;

  const size_t wm_elems = (size_t)OUT_DIM * IN_DIM;
  const size_t xb_elems = (size_t)BATCH * IN_DIM;
  const size_t out_elems = (size_t)BATCH * OUT_DIM;
  const size_t need_bf16 = (wm_elems + xb_elems) * sizeof(short);   // 288 MiB
  const size_t need_split = need_bf16 + out_elems * sizeof(float);  // 320 MiB

  if (ws_size >= need_split) {
    short* wmb = (short*)d_ws;
    short* xbb = wmb + wm_elems;
    float* p1 = (float*)((char*)d_ws + need_bf16);
    hipLaunchKernelGGL(prep_w_kernel, dim3(4096), dim3(256), 0, stream,
                       (const f32x4*)w, (const f32x4*)mask, (u16x8*)wmb,
                       (int)(wm_elems / 8));
    hipLaunchKernelGGL(prep_x_kernel, dim3(512), dim3(256), 0, stream,
                       (const f32x4*)x, (u16x8*)xbb, (int)(xb_elems / 8));
    hipLaunchKernelGGL(gemm256, dim3(KSPLIT * MT256 * NT256), dim3(1024), 0,
                       stream, xbb, wmb, out, p1);
    hipLaunchKernelGGL(reduce_kernel, dim3(2048), dim3(256), 0, stream,
                       (const f32x4*)out, (const f32x4*)p1,
                       (const f32x4*)bias, (f32x4*)out, (int)(out_elems / 4));
  } else {
    hipLaunchKernelGGL(gemm128_fused, dim3(512), dim3(256), 0, stream, x, w,
                       mask, bias, out);
  }
}